// Round 3
// baseline (91.374 us; speedup 1.0000x reference)
//
#include <hip/hip_runtime.h>

// GroupAvgPool1d: x [B,N,C] fp32, y [B,N] int group ids, G groups.
// d_out = feature [B,G,C] fp32 ++ mask [B,G] (0.0/1.0).
// Shapes fixed: B=16, N=8192, C=64, G=512.
//
// v3: index-compaction gather. Scan y from LDS as before, but instead of
// issuing one dependent load per match (MLP=1, latency-serialized), compact
// match indices into a per-wave LDS buffer and gather in unrolled batches of
// 8 independent loads into 8 accumulators (MLP=8). Deterministic, no atomics,
// x read exactly once, fully coalesced 256B/row.

#define B_ 16
#define N_ 8192
#define C_ 64
#define G_ 512
#define CHUNK 1024            // y ids staged per iteration (4 KB LDS)
#define NCHUNK (N_ / CHUNK)   // 8
#define CAP 272               // per-wave index buffer (max 7 carry + 256 new)

__global__ __launch_bounds__(256, 8)
void gap_gather3(const float* __restrict__ x, const int* __restrict__ y,
                 float* __restrict__ feature, float* __restrict__ maskout) {
    const int tid  = threadIdx.x;
    const int lane = tid & 63;
    const int wave = tid >> 6;
    const int blk  = blockIdx.x;            // 0 .. B*G/4 - 1
    const int b    = blk >> 7;              // / (G/4 = 128)
    const int g    = ((blk & 127) << 2) + wave;

    const int*   yb = y + b * N_;
    const float* xb = x + (size_t)b * (size_t)(N_ * C_);

    __shared__ int sy[CHUNK];
    __shared__ int widx[4][CAP];            // row base 1088 B -> 16B aligned

    float a0 = 0, a1 = 0, a2 = 0, a3 = 0, a4 = 0, a5 = 0, a6 = 0, a7 = 0;
    int cnt = 0;   // pending (unflushed) match indices in widx[wave]
    int tot = 0;   // total matches (for mask)

    // prefetch y chunk 0 (one int4 per thread = 1024 ids/block)
    int4 pre = *reinterpret_cast<const int4*>(yb + tid * 4);

    for (int ch = 0; ch < NCHUNK; ++ch) {
        __syncthreads();                    // all waves done reading sy
        *reinterpret_cast<int4*>(&sy[tid * 4]) = pre;
        __syncthreads();                    // sy ready
        if (ch + 1 < NCHUNK)
            pre = *reinterpret_cast<const int4*>(yb + (ch + 1) * CHUNK + tid * 4);

        const int nbase = ch * CHUNK;
        for (int sub = 0; sub < CHUNK / 256; ++sub) {
            const int4 yv = *reinterpret_cast<const int4*>(&sy[sub * 256 + lane * 4]);
            const int nl = nbase + sub * 256 + lane * 4;

            // --- compact match indices (prefix-count via mbcnt) ---
            #define COMPACT(VAL, OFF) do {                                        \
                unsigned long long m = __ballot((VAL) == g);                      \
                int p = __builtin_amdgcn_mbcnt_hi((unsigned)(m >> 32),            \
                        __builtin_amdgcn_mbcnt_lo((unsigned)m, 0));               \
                if ((VAL) == g) widx[wave][cnt + p] = nl + (OFF);                 \
                int pc = (int)__popcll(m);                                        \
                cnt += pc; tot += pc;                                             \
            } while (0)
            COMPACT(yv.x, 0);
            COMPACT(yv.y, 1);
            COMPACT(yv.z, 2);
            COMPACT(yv.w, 3);
            #undef COMPACT

            // --- flush in batches of 8 independent loads (MLP=8) ---
            int fo = 0;
            while (cnt - fo >= 8) {
                // broadcast reads: all lanes read same 16B (no conflicts)
                const int4 ia = *reinterpret_cast<const int4*>(&widx[wave][fo]);
                const int4 ib = *reinterpret_cast<const int4*>(&widx[wave][fo + 4]);
                a0 += xb[(size_t)ia.x * C_ + lane];
                a1 += xb[(size_t)ia.y * C_ + lane];
                a2 += xb[(size_t)ia.z * C_ + lane];
                a3 += xb[(size_t)ia.w * C_ + lane];
                a4 += xb[(size_t)ib.x * C_ + lane];
                a5 += xb[(size_t)ib.y * C_ + lane];
                a6 += xb[(size_t)ib.z * C_ + lane];
                a7 += xb[(size_t)ib.w * C_ + lane];
                fo += 8;
            }
            const int rem = cnt - fo;
            if (fo > 0 && rem > 0) {        // move leftover (<8) to front
                int t = (lane < rem) ? widx[wave][fo + lane] : 0;
                if (lane < rem) widx[wave][lane] = t;
            }
            cnt = rem;
        }
    }

    // tail: <8 leftover indices, serial is fine
    for (int i = 0; i < cnt; ++i)
        a0 += xb[(size_t)widx[wave][i] * C_ + lane];

    const float acc = ((a0 + a1) + (a2 + a3)) + ((a4 + a5) + (a6 + a7));
    feature[((size_t)b * G_ + g) * C_ + lane] = acc * (1.0f / (float)N_);
    if (lane == 0) maskout[b * G_ + g] = (tot > 0) ? 1.0f : 0.0f;
}

extern "C" void kernel_launch(void* const* d_in, const int* in_sizes, int n_in,
                              void* d_out, int out_size, void* d_ws, size_t ws_size,
                              hipStream_t stream) {
    const float* x = (const float*)d_in[0];
    const int*   y = (const int*)d_in[1];
    float* feature = (float*)d_out;                        // B*G*C floats
    float* maskout = (float*)d_out + (size_t)B_ * G_ * C_; // B*G floats

    const int grid = B_ * (G_ / 4);   // 2048 blocks x 256 threads (4 waves)
    gap_gather3<<<grid, 256, 0, stream>>>(x, y, feature, maskout);
}